// Round 8
// baseline (2509.540 us; speedup 1.0000x reference)
//
#include <hip/hip_runtime.h>
#include <math.h>

#define DIM 128
#define KC 1024
#define NITER 10
#define BM 128
#define NB 512   // scatter blocks: n / 256
#define THRESH 0.01f  // bf16 3-term screen-vs-frozen worst-case ~2e-3; 5x margin

typedef __bf16 bf16x8 __attribute__((ext_vector_type(8)));
typedef float f32x4 __attribute__((ext_vector_type(4)));

// round-to-nearest-even fp32 -> bf16 (NaN-preserving)
__device__ __forceinline__ unsigned short bf16rne(float f) {
    unsigned int u = __float_as_uint(f);
    unsigned int r = (u + 0x7FFFu + ((u >> 16) & 1u)) >> 16;
    return (unsigned short)r;
}

__device__ __forceinline__ bf16x8 pack_hi8(const float* fv, unsigned short* hs) {
    bf16x8 out;
    #pragma unroll
    for (int e = 0; e < 8; e++) {
        unsigned short h = bf16rne(fv[e]);
        hs[e] = h;
        out[e] = __builtin_bit_cast(__bf16, h);
    }
    return out;
}

// ---- numpy-pairwise sum of squares over one 128-float row, frozen chain.
// Shared by sq_np_kernel and the fused csq path in sum_kernel: the ops are
// exact IEEE (__fmul_rn/__fadd_rn) in a fixed order -> bit-exact anywhere.
__device__ __forceinline__ float sq_np_row(const float* __restrict__ v) {
    const float4* row = (const float4*)v;
    float r[8];
    {
        float4 a = row[0], b = row[1];
        r[0] = __fmul_rn(a.x, a.x); r[1] = __fmul_rn(a.y, a.y);
        r[2] = __fmul_rn(a.z, a.z); r[3] = __fmul_rn(a.w, a.w);
        r[4] = __fmul_rn(b.x, b.x); r[5] = __fmul_rn(b.y, b.y);
        r[6] = __fmul_rn(b.z, b.z); r[7] = __fmul_rn(b.w, b.w);
    }
    #pragma unroll
    for (int blk = 1; blk < 16; blk++) {
        float4 a = row[blk * 2], b = row[blk * 2 + 1];
        r[0] = __fadd_rn(r[0], __fmul_rn(a.x, a.x));
        r[1] = __fadd_rn(r[1], __fmul_rn(a.y, a.y));
        r[2] = __fadd_rn(r[2], __fmul_rn(a.z, a.z));
        r[3] = __fadd_rn(r[3], __fmul_rn(a.w, a.w));
        r[4] = __fadd_rn(r[4], __fmul_rn(b.x, b.x));
        r[5] = __fadd_rn(r[5], __fmul_rn(b.y, b.y));
        r[6] = __fadd_rn(r[6], __fmul_rn(b.z, b.z));
        r[7] = __fadd_rn(r[7], __fmul_rn(b.w, b.w));
    }
    return __fadd_rn(__fadd_rn(__fadd_rn(r[0], r[1]), __fadd_rn(r[2], r[3])),
                     __fadd_rn(__fadd_rn(r[4], r[5]), __fadd_rn(r[6], r[7])));
}

__global__ void sq_np_kernel(const float* __restrict__ v, float* __restrict__ out, int rows) {
    int i = blockIdx.x * blockDim.x + threadIdx.x;
    if (i >= rows) return;
    out[i] = sq_np_row(v + (size_t)i * DIM);
}

// ---- MFMA screen, register-resident A, zero LDS, zero barriers ----
// bf16 3-term split (hh + lh + hl), THRESH 0.01 (R5/R7-proven fb logic).
// NEW: B hi-fragments double-buffered (prefetch kt+1 during kt's MFMAs);
// MFMA order = all-hh, all-lh (bh-only terms first), then all-hl -- the
// just-issued bl loads get ~16 MFMAs of latency cover, the prefetched bh
// covers the rest. Screen summation order changes (fp32-commutative within
// the THRESH error budget); fb semantics and frozen paths untouched.
__global__ __launch_bounds__(256, 3) void assign_mfma_kernel(
    const float* __restrict__ x,
    const ushort* __restrict__ centPh, const ushort* __restrict__ centPl,
    const float* __restrict__ csq,
    int* __restrict__ cl, int* __restrict__ fb_list, int* __restrict__ fbc)
{
    const int tid = threadIdx.x;
    const int lane = tid & 63;
    const int w = tid >> 6;                 // wave 0..3 -> 32-point group
    const int bm = blockIdx.x * BM;
    const int row0 = bm + w * 32 + (lane & 15);
    const int ko = (lane >> 4) * 8;         // k-oct 0,8,16,24

    // ---- load + split A fragments (kt-invariant) ----
    bf16x8 ah[2][4], al[2][4];
    #pragma unroll
    for (int m = 0; m < 2; m++) {
        const float* xr = x + (size_t)(row0 + m * 16) * DIM;
        #pragma unroll
        for (int dt = 0; dt < 4; dt++) {
            float4 a = *(const float4*)(xr + dt * 32 + ko);
            float4 b = *(const float4*)(xr + dt * 32 + ko + 4);
            float fv[8] = {a.x, a.y, a.z, a.w, b.x, b.y, b.z, b.w};
            unsigned short hs[8];
            ah[m][dt] = pack_hi8(fv, hs);
            bf16x8 lo;
            #pragma unroll
            for (int e = 0; e < 8; e++) {
                float rem = __fsub_rn(fv[e], __uint_as_float(((unsigned int)hs[e]) << 16));
                lo[e] = __builtin_bit_cast(__bf16, bf16rne(rem));
            }
            al[m][dt] = lo;
        }
    }

    float best1[8], best2[8];
    int bidx[8];
    int nanf = 0;
    #pragma unroll
    for (int s = 0; s < 8; s++) { best1[s] = INFINITY; best2[s] = INFINITY; bidx[s] = 0; }

    const ushort* pb = centPh + lane * 8;
    const ushort* qb = centPl + lane * 8;

#define MFMA_(A, B, C) __builtin_amdgcn_mfma_f32_16x16x32_bf16(A, B, C, 0, 0, 0)

    // prologue: hi fragments of kt=0
    bf16x8 bhP0 = *(const bf16x8*)(pb);
    bf16x8 bhP1 = *(const bf16x8*)(pb + 512);
    bf16x8 bhP2 = *(const bf16x8*)(pb + 1024);
    bf16x8 bhP3 = *(const bf16x8*)(pb + 1536);
    bf16x8 bhQ0, bhQ1, bhQ2, bhQ3;

    // NOTE: the last phase (kt=63) prefetches pb + 64*2048 which lands at the
    // start of the adjacent centPl allocation -- mapped memory, never used.
#define PHASE(KT, B0, B1, B2, B3, N0, N1, N2, N3)                            \
    {                                                                        \
        const ushort* qk = qb + (size_t)(KT) * 2048;                         \
        bf16x8 bl0 = *(const bf16x8*)(qk);                                   \
        bf16x8 bl1 = *(const bf16x8*)(qk + 512);                             \
        bf16x8 bl2 = *(const bf16x8*)(qk + 1024);                            \
        bf16x8 bl3 = *(const bf16x8*)(qk + 1536);                            \
        const ushort* pn = pb + (size_t)((KT) + 1) * 2048;                   \
        N0 = *(const bf16x8*)(pn);                                           \
        N1 = *(const bf16x8*)(pn + 512);                                     \
        N2 = *(const bf16x8*)(pn + 1024);                                    \
        N3 = *(const bf16x8*)(pn + 1536);                                    \
        f32x4 a0 = (f32x4){0.f, 0.f, 0.f, 0.f};                              \
        f32x4 a1 = (f32x4){0.f, 0.f, 0.f, 0.f};                              \
        a0 = MFMA_(ah[0][0], B0, a0);  a1 = MFMA_(ah[1][0], B0, a1);         \
        a0 = MFMA_(ah[0][1], B1, a0);  a1 = MFMA_(ah[1][1], B1, a1);         \
        a0 = MFMA_(ah[0][2], B2, a0);  a1 = MFMA_(ah[1][2], B2, a1);         \
        a0 = MFMA_(ah[0][3], B3, a0);  a1 = MFMA_(ah[1][3], B3, a1);         \
        a0 = MFMA_(al[0][0], B0, a0);  a1 = MFMA_(al[1][0], B0, a1);         \
        a0 = MFMA_(al[0][1], B1, a0);  a1 = MFMA_(al[1][1], B1, a1);         \
        a0 = MFMA_(al[0][2], B2, a0);  a1 = MFMA_(al[1][2], B2, a1);         \
        a0 = MFMA_(al[0][3], B3, a0);  a1 = MFMA_(al[1][3], B3, a1);         \
        a0 = MFMA_(ah[0][0], bl0, a0); a1 = MFMA_(ah[1][0], bl0, a1);        \
        a0 = MFMA_(ah[0][1], bl1, a0); a1 = MFMA_(ah[1][1], bl1, a1);        \
        a0 = MFMA_(ah[0][2], bl2, a0); a1 = MFMA_(ah[1][2], bl2, a1);        \
        a0 = MFMA_(ah[0][3], bl3, a0); a1 = MFMA_(ah[1][3], bl3, a1);        \
        int kk = (KT) * 16 + (lane & 15);                                    \
        float cq = csq[kk];                                                  \
        nanf |= (cq != cq) ? 1 : 0;                                          \
        _Pragma("unroll")                                                    \
        for (int q = 0; q < 4; q++) {                                        \
            {                                                                \
                float d = __fmaf_rn(-2.f, a0[q], cq);                        \
                bool lt = (d < best1[q]);                                    \
                best2[q] = fminf(best2[q], lt ? best1[q] : d);               \
                if (lt) { best1[q] = d; bidx[q] = kk; }                      \
            }                                                                \
            {                                                                \
                int s = 4 + q;                                               \
                float d = __fmaf_rn(-2.f, a1[q], cq);                        \
                bool lt = (d < best1[s]);                                    \
                best2[s] = fminf(best2[s], lt ? best1[s] : d);               \
                if (lt) { best1[s] = d; bidx[s] = kk; }                      \
            }                                                                \
        }                                                                    \
    }

    for (int kt = 0; kt < KC / 16; kt += 2) {
        PHASE(kt,     bhP0, bhP1, bhP2, bhP3, bhQ0, bhQ1, bhQ2, bhQ3)
        PHASE(kt + 1, bhQ0, bhQ1, bhQ2, bhQ3, bhP0, bhP1, bhP2, bhP3)
    }
#undef PHASE
#undef MFMA_

    // butterfly merge across the 16 cluster-lanes (same lane>>4 group)
    #pragma unroll
    for (int mask = 1; mask < 16; mask <<= 1) {
        #pragma unroll
        for (int s = 0; s < 8; s++) {
            float ob1 = __shfl_xor(best1[s], mask, 64);
            float ob2 = __shfl_xor(best2[s], mask, 64);
            int   oi  = __shfl_xor(bidx[s],  mask, 64);
            float nb2 = fminf(fminf(best2[s], ob2), fmaxf(best1[s], ob1));
            bool take = (ob1 < best1[s]) || (ob1 == best1[s] && oi < bidx[s]);
            if (take) { best1[s] = ob1; bidx[s] = oi; }
            best2[s] = nb2;
        }
    }

    int wnan = __any(nanf);
    if ((lane & 15) == 0) {
        int hi = lane >> 4;
        #pragma unroll
        for (int s = 0; s < 8; s++) {
            int p = bm + w * 32 + (s >> 2) * 16 + hi * 4 + (s & 3);
            bool fb = (wnan != 0) || !(best2[s] - best1[s] > THRESH);
            if (fb) { int pos = atomicAdd(fbc, 1); fb_list[pos] = p; }
            else cl[p] = bidx[s];
        }
    }
}

// frozen comparator: NaN acts as -inf tier, lowest index on ties (first-min/first-NaN)
__device__ __forceinline__ bool better(float od, int oi, float md, int mi) {
    bool n1 = (md != md), n2 = (od != od);
    if (n1 && n2) return oi < mi;
    if (n2) return true;
    if (n1) return false;
    return (od < md) || (od == md && oi < mi);
}

// ---- exact fallback: replay the frozen fp32 fmaf chain over all K.
// 16 points per block pass; d-loop unrolled 4x (16 centTf loads in flight).
// Unrolling interleaves INDEPENDENT (point,cluster) chains only -- each
// chain keeps its frozen d-ascending order. centTf[d][k] fp32 transposed
// -> coalesced; rounding identical to row-major chain. ----
__global__ __launch_bounds__(256) void fixup_kernel(
    const float* __restrict__ x, const float* __restrict__ centTf,
    const float* __restrict__ xsq, const float* __restrict__ csq,
    const int* __restrict__ fb_list, const int* __restrict__ fbc,
    int* __restrict__ cl)
{
    __shared__ float xs[16][DIM];   // 8 KB
    __shared__ float xqs[16];
    __shared__ int   ids[16];
    __shared__ float wv[16][4];
    __shared__ int   wi[16][4];
    const int t = threadIdx.x;
    const int lane = t & 63, wid = t >> 6;
    const int cnt = fbc[0];
    for (int w = blockIdx.x * 16; w < cnt; w += gridDim.x * 16) {
        int np = cnt - w; if (np > 16) np = 16;
        __syncthreads();                 // guard xs/wv reuse from prior pass
        if (t < np) { int i = fb_list[w + t]; ids[t] = i; xqs[t] = xsq[i]; }
        __syncthreads();
        for (int e = t; e < np * DIM; e += 256) {
            int p = e >> 7, d = e & 127;
            xs[p][d] = x[(size_t)ids[p] * DIM + d];
        }
        __syncthreads();
        float S[16][4];
        #pragma unroll
        for (int p = 0; p < 16; p++)
            #pragma unroll
            for (int c = 0; c < 4; c++) S[p][c] = 0.f;
        #pragma unroll 4
        for (int d = 0; d < DIM; d++) {
            const float* row = centTf + (size_t)d * KC;
            float c0 = row[t], c1 = row[t + 256], c2 = row[t + 512], c3 = row[t + 768];
            #pragma unroll
            for (int p = 0; p < 16; p++) {
                float xv = xs[p][d];
                S[p][0] = fmaf(xv, c0, S[p][0]);   // frozen chain, d ascending
                S[p][1] = fmaf(xv, c1, S[p][1]);
                S[p][2] = fmaf(xv, c2, S[p][2]);
                S[p][3] = fmaf(xv, c3, S[p][3]);
            }
        }
        float q0 = csq[t], q1 = csq[t + 256], q2 = csq[t + 512], q3 = csq[t + 768];
        #pragma unroll
        for (int p = 0; p < 16; p++) {
            float xq = xqs[p];
            float bb = INFINITY; int bi = 0x7fffffff;
            float dd; int c;
            c = t;       dd = __fadd_rn(__fsub_rn(xq, __fmul_rn(2.f, S[p][0])), q0); if (better(dd, c, bb, bi)) { bb = dd; bi = c; }
            c = t + 256; dd = __fadd_rn(__fsub_rn(xq, __fmul_rn(2.f, S[p][1])), q1); if (better(dd, c, bb, bi)) { bb = dd; bi = c; }
            c = t + 512; dd = __fadd_rn(__fsub_rn(xq, __fmul_rn(2.f, S[p][2])), q2); if (better(dd, c, bb, bi)) { bb = dd; bi = c; }
            c = t + 768; dd = __fadd_rn(__fsub_rn(xq, __fmul_rn(2.f, S[p][3])), q3); if (better(dd, c, bb, bi)) { bb = dd; bi = c; }
            #pragma unroll
            for (int mask = 1; mask < 64; mask <<= 1) {
                float od = __shfl_xor(bb, mask, 64);
                int   oi = __shfl_xor(bi, mask, 64);
                if (better(od, oi, bb, bi)) { bb = od; bi = oi; }
            }
            if (lane == 0) { wv[p][wid] = bb; wi[p][wid] = bi; }
        }
        __syncthreads();
        if (t < np) {
            float bb = wv[t][0]; int bi = wi[t][0];
            #pragma unroll
            for (int r = 1; r < 4; r++)
                if (better(wv[t][r], wi[t][r], bb, bi)) { bb = wv[t][r]; bi = wi[t][r]; }
            cl[ids[t]] = bi;
        }
    }
}

// ---- stable counting-scatter: list[] = per-cluster ascending point index ----

__global__ __launch_bounds__(256) void bhist_kernel(const int* __restrict__ cl,
                                                    int* __restrict__ bhist, int n,
                                                    int* __restrict__ fbc) {
    __shared__ int h[KC];
    int t = threadIdx.x;
    // fold the fbc reset here: bhist runs after fixup consumed fbc[0] and
    // before the next iteration's assign (stream order) -- race-free.
    if (blockIdx.x == 0 && t == 0) { fbc[0] = 0; fbc[1] = 0; }
    #pragma unroll
    for (int q = 0; q < KC / 256; q++) h[t + q * 256] = 0;
    __syncthreads();
    int i = blockIdx.x * 256 + t;
    if (i < n) atomicAdd(&h[cl[i]], 1);
    __syncthreads();
    int* row = bhist + (size_t)blockIdx.x * KC;
    #pragma unroll
    for (int q = 0; q < KC / 256; q++) row[t + q * 256] = h[t + q * 256];
}

__global__ __launch_bounds__(256) void colsum_kernel(const int* __restrict__ bhist,
                                                     int* __restrict__ cnt) {
    int k = blockIdx.x * 256 + threadIdx.x;
    int s = 0;
    for (int b = 0; b < NB; b++) s += bhist[(size_t)b * KC + k];
    cnt[k] = s;
}

__global__ void scan_kernel(const int* __restrict__ cnt, int* __restrict__ off) {
    __shared__ int s[KC];
    int t = threadIdx.x;
    s[t] = cnt[t];
    __syncthreads();
    for (int o = 1; o < KC; o <<= 1) {
        int v = (t >= o) ? s[t - o] : 0;
        __syncthreads();
        s[t] += v;
        __syncthreads();
    }
    off[t] = s[t] - cnt[t];
}

__global__ __launch_bounds__(256) void blockpfx_kernel(int* __restrict__ bhist,
                                                       const int* __restrict__ off) {
    int k = blockIdx.x * 256 + threadIdx.x;
    int run = off[k];
    for (int b = 0; b < NB; b++) {
        size_t idx = (size_t)b * KC + k;
        int t = bhist[idx];
        bhist[idx] = run;
        run += t;
    }
}

__global__ __launch_bounds__(256) void stable_scatter_kernel(
    const int* __restrict__ cl, const int* __restrict__ bhist,
    int* __restrict__ list, int n)
{
    __shared__ int cls[256];
    int t = threadIdx.x;
    int i = blockIdx.x * 256 + t;
    int c = (i < n) ? cl[i] : -1;
    cls[t] = c;
    __syncthreads();
    if (i >= n) return;
    int rank = 0;
    for (int j = 0; j < 256; j++)
        rank += (j < t && cls[j] == c) ? 1 : 0;
    list[bhist[(size_t)blockIdx.x * KC + c] + rank] = i;
}

// ---- segment sum: bitwise-ordered adds; writes cent, the bf16 hi/lo
// fragment-packed centP, the fp32 transposed centTf (fixup path), AND csq
// (frozen pairwise chain replayed from LDS -- removes a dispatch/iter) ----
#define CHUNK 512
__global__ __launch_bounds__(128) void sum_kernel(
    const float* __restrict__ x, const int* __restrict__ list,
    const int* __restrict__ off, const int* __restrict__ cnt,
    float* __restrict__ cent, ushort* __restrict__ centPh,
    ushort* __restrict__ centPl, float* __restrict__ centTf,
    float* __restrict__ csq, float* __restrict__ countsF)
{
    __attribute__((aligned(16))) __shared__ int sidx[CHUNK];   // 2 KB; reused below
    int k = blockIdx.x;
    int d = threadIdx.x;
    int o = off[k], m = cnt[k];
    float s = 0.f;
    for (int base = 0; base < m; base += CHUNK) {
        int c = m - base; if (c > CHUNK) c = CHUNK;
        __syncthreads();
        for (int t = d; t < c; t += 128) sidx[t] = list[o + base + t];
        __syncthreads();
        int j = 0;
        for (; j + 16 <= c; j += 16) {
            float v[16];
            #pragma unroll
            for (int u = 0; u < 16; u++)
                v[u] = x[(size_t)sidx[j + u] * DIM + d];
            #pragma unroll
            for (int u = 0; u < 16; u++)
                s = __fadd_rn(s, v[u]);
        }
        for (; j < c; j++)
            s = __fadd_rn(s, x[(size_t)sidx[j] * DIM + d]);
    }
    float mv = __fdiv_rn(s, (float)m);   // 0/0 -> NaN, matches ref
    cent[(size_t)k * DIM + d] = mv;
    centTf[(size_t)d * KC + k] = mv;
    unsigned short h = bf16rne(mv);
    unsigned short lo = bf16rne(__fsub_rn(mv, __uint_as_float(((unsigned int)h) << 16)));
    int pidx = (((k >> 4) * 4 + (d >> 5)) * 64 + ((k & 15) + 16 * ((d >> 3) & 3))) * 8 + (d & 7);
    centPh[pidx] = h;
    centPl[pidx] = lo;
    if (d == 0) countsF[k] = (float)m;
    // fused csq: replay the frozen pairwise chain on this centroid row
    __syncthreads();
    ((float*)sidx)[d] = mv;
    __syncthreads();
    if (d == 0) csq[k] = sq_np_row((const float*)sidx);
}

__global__ void init_centP_kernel(const float* __restrict__ x,
                                  ushort* __restrict__ centPh, ushort* __restrict__ centPl,
                                  float* __restrict__ centTf, int* __restrict__ fbc) {
    int i = blockIdx.x * 256 + threadIdx.x;
    if (i == 0) { fbc[0] = 0; fbc[1] = 0; }
    if (i < KC * DIM) {
        int k = i >> 7, d = i & 127;
        float v = x[i];
        centTf[(size_t)d * KC + k] = v;
        unsigned short h = bf16rne(v);
        unsigned short lo = bf16rne(__fsub_rn(v, __uint_as_float(((unsigned int)h) << 16)));
        int pidx = (((k >> 4) * 4 + (d >> 5)) * 64 + ((k & 15) + 16 * ((d >> 3) & 3))) * 8 + (d & 7);
        centPh[pidx] = h;
        centPl[pidx] = lo;
    }
}

__global__ void cl2f_kernel(const int* __restrict__ cl, float* __restrict__ out, int n) {
    int i = blockIdx.x * 256 + threadIdx.x;
    if (i < n) out[i] = (float)cl[i];
}

extern "C" void kernel_launch(void* const* d_in, const int* in_sizes, int n_in,
                              void* d_out, int out_size, void* d_ws, size_t ws_size,
                              hipStream_t stream) {
    const float* x = (const float*)d_in[0];
    const int n = in_sizes[0] / DIM;  // 131072

    // d_out: [clusters (N) | centroids (K*D) | counts (K)]
    float* clf     = (float*)d_out;
    float* cent    = clf + n;
    float* countsF = cent + KC * DIM;

    // ws scratch (~4.1 MB, same footprint as before)
    float* xsq   = (float*)d_ws;          // N
    float* csq   = xsq + n;               // K
    int*   cl    = (int*)(csq + KC);      // N
    int*   list  = cl + n;                // N (doubles as fb_list before scatter)
    int*   cnt   = list + n;              // K
    int*   off   = cnt + KC;              // K
    int*   bhist = off + KC;              // NB*K (2 MB)
    ushort* centPh = (ushort*)(bhist + (size_t)NB * KC);  // K*D bf16 hi (256 KB)
    ushort* centPl = centPh + KC * DIM;                   // K*D bf16 lo (256 KB)
    int*   fbc   = (int*)(centPl + KC * DIM);             // [count, cursor]
    // centTf (fp32 [D][K], 512 KB) ALIASES bhist: written by sum (end of
    // iter i) / init, read by fixup (early iter i+1), clobbered only by
    // bhist_kernel which runs after fixup in stream order. Time-disjoint.
    float* centTf = (float*)bhist;

    hipMemcpyAsync(cent, x, (size_t)KC * DIM * sizeof(float),
                   hipMemcpyDeviceToDevice, stream);
    init_centP_kernel<<<(KC * DIM + 255) / 256, 256, 0, stream>>>(x, centPh, centPl,
                                                                  centTf, fbc);
    sq_np_kernel<<<(n + 255) / 256, 256, 0, stream>>>(x, xsq, n);
    // iter-0 centroids are x[:K], so csq == xsq[:K] bit-exact (same chain)
    hipMemcpyAsync(csq, xsq, (size_t)KC * sizeof(float),
                   hipMemcpyDeviceToDevice, stream);

    for (int it = 0; it < NITER; it++) {
        assign_mfma_kernel<<<n / BM, 256, 0, stream>>>(x, centPh, centPl, csq,
                                                       cl, list, fbc);
        fixup_kernel<<<1024, 256, 0, stream>>>(x, centTf, xsq, csq, list, fbc, cl);
        bhist_kernel<<<NB, 256, 0, stream>>>(cl, bhist, n, fbc);
        colsum_kernel<<<KC / 256, 256, 0, stream>>>(bhist, cnt);
        scan_kernel<<<1, KC, 0, stream>>>(cnt, off);
        blockpfx_kernel<<<KC / 256, 256, 0, stream>>>(bhist, off);
        stable_scatter_kernel<<<NB, 256, 0, stream>>>(cl, bhist, list, n);
        sum_kernel<<<KC, DIM, 0, stream>>>(x, list, off, cnt, cent, centPh, centPl,
                                           centTf, csq, countsF);
    }

    cl2f_kernel<<<(n + 255) / 256, 256, 0, stream>>>(cl, clf, n);
}

// Round 9
// 2235.188 us; speedup vs baseline: 1.1227x; 1.1227x over previous
//
#include <hip/hip_runtime.h>
#include <math.h>

#define DIM 128
#define KC 1024
#define NITER 10
#define BM 128
#define NB 512   // scatter blocks: n / 256
#define THRESH 0.01f  // bf16 3-term screen-vs-frozen worst-case ~2e-3; 5x margin

typedef __bf16 bf16x8 __attribute__((ext_vector_type(8)));
typedef float f32x4 __attribute__((ext_vector_type(4)));

// round-to-nearest-even fp32 -> bf16 (NaN-preserving)
__device__ __forceinline__ unsigned short bf16rne(float f) {
    unsigned int u = __float_as_uint(f);
    unsigned int r = (u + 0x7FFFu + ((u >> 16) & 1u)) >> 16;
    return (unsigned short)r;
}

__device__ __forceinline__ bf16x8 pack_hi8(const float* fv, unsigned short* hs) {
    bf16x8 out;
    #pragma unroll
    for (int e = 0; e < 8; e++) {
        unsigned short h = bf16rne(fv[e]);
        hs[e] = h;
        out[e] = __builtin_bit_cast(__bf16, h);
    }
    return out;
}

// ---- numpy-pairwise sum of squares over one 128-float row, frozen chain.
// Shared by sq_np_kernel and the fused csq path in sum_kernel: the ops are
// exact IEEE (__fmul_rn/__fadd_rn) in a fixed order -> bit-exact anywhere.
__device__ __forceinline__ float sq_np_row(const float* __restrict__ v) {
    const float4* row = (const float4*)v;
    float r[8];
    {
        float4 a = row[0], b = row[1];
        r[0] = __fmul_rn(a.x, a.x); r[1] = __fmul_rn(a.y, a.y);
        r[2] = __fmul_rn(a.z, a.z); r[3] = __fmul_rn(a.w, a.w);
        r[4] = __fmul_rn(b.x, b.x); r[5] = __fmul_rn(b.y, b.y);
        r[6] = __fmul_rn(b.z, b.z); r[7] = __fmul_rn(b.w, b.w);
    }
    #pragma unroll
    for (int blk = 1; blk < 16; blk++) {
        float4 a = row[blk * 2], b = row[blk * 2 + 1];
        r[0] = __fadd_rn(r[0], __fmul_rn(a.x, a.x));
        r[1] = __fadd_rn(r[1], __fmul_rn(a.y, a.y));
        r[2] = __fadd_rn(r[2], __fmul_rn(a.z, a.z));
        r[3] = __fadd_rn(r[3], __fmul_rn(a.w, a.w));
        r[4] = __fadd_rn(r[4], __fmul_rn(b.x, b.x));
        r[5] = __fadd_rn(r[5], __fmul_rn(b.y, b.y));
        r[6] = __fadd_rn(r[6], __fmul_rn(b.z, b.z));
        r[7] = __fadd_rn(r[7], __fmul_rn(b.w, b.w));
    }
    return __fadd_rn(__fadd_rn(__fadd_rn(r[0], r[1]), __fadd_rn(r[2], r[3])),
                     __fadd_rn(__fadd_rn(r[4], r[5]), __fadd_rn(r[6], r[7])));
}

__global__ void sq_np_kernel(const float* __restrict__ v, float* __restrict__ out, int rows) {
    int i = blockIdx.x * blockDim.x + threadIdx.x;
    if (i >= rows) return;
    out[i] = sq_np_row(v + (size_t)i * DIM);
}

// ---- MFMA screen, register-resident A, zero LDS, zero barriers ----
// (R5/R7-proven loop: bf16 3-term split, simple per-kt loads, compiler
// scheduling, VGPR 60, 4 waves/SIMD -- the empirical optimum of 5 variants:
// LDS 270us / 512t 320us / THIS 116us / f16 192us / sw-pipelined 163us.
// Cross-wave TLP hides L2 latency better than in-wave prefetch here.)
// Each wave owns 32 points x ALL 1024 clusters. A-fragments (hi/lo split
// bf16) loaded once from global x per MFMA lane mapping (row=lane&15,
// k-oct=lane>>4), kt-invariant -> 64 persistent VGPRs. B-fragments read
// from packed centP (L1/L2-resident, shared by all waves/CU).
// Score d' = csq - 2*dot (shift by -xsq preserves argmin and gap).
// 2-min tracking; gap <= THRESH or NaN-wave -> exact fallback.
__global__ __launch_bounds__(256, 3) void assign_mfma_kernel(
    const float* __restrict__ x,
    const ushort* __restrict__ centPh, const ushort* __restrict__ centPl,
    const float* __restrict__ csq,
    int* __restrict__ cl, int* __restrict__ fb_list, int* __restrict__ fbc)
{
    const int tid = threadIdx.x;
    const int lane = tid & 63;
    const int w = tid >> 6;                 // wave 0..3 -> 32-point group
    const int bm = blockIdx.x * BM;
    const int row0 = bm + w * 32 + (lane & 15);
    const int ko = (lane >> 4) * 8;         // k-oct 0,8,16,24

    // ---- load + split A fragments (kt-invariant) ----
    bf16x8 ah[2][4], al[2][4];
    #pragma unroll
    for (int m = 0; m < 2; m++) {
        const float* xr = x + (size_t)(row0 + m * 16) * DIM;
        #pragma unroll
        for (int dt = 0; dt < 4; dt++) {
            float4 a = *(const float4*)(xr + dt * 32 + ko);
            float4 b = *(const float4*)(xr + dt * 32 + ko + 4);
            float fv[8] = {a.x, a.y, a.z, a.w, b.x, b.y, b.z, b.w};
            unsigned short hs[8];
            ah[m][dt] = pack_hi8(fv, hs);
            bf16x8 lo;
            #pragma unroll
            for (int e = 0; e < 8; e++) {
                float rem = __fsub_rn(fv[e], __uint_as_float(((unsigned int)hs[e]) << 16));
                lo[e] = __builtin_bit_cast(__bf16, bf16rne(rem));
            }
            al[m][dt] = lo;
        }
    }

    float best1[8], best2[8];
    int bidx[8];
    int nanf = 0;
    #pragma unroll
    for (int s = 0; s < 8; s++) { best1[s] = INFINITY; best2[s] = INFINITY; bidx[s] = 0; }

    const ushort* pb = centPh + lane * 8;
    const ushort* qb = centPl + lane * 8;
    int kk = lane & 15;

    for (int kt = 0; kt < KC / 16; kt++) {
        const ushort* pk = pb + (size_t)kt * 2048;
        const ushort* qk = qb + (size_t)kt * 2048;
        bf16x8 bh0 = *(const bf16x8*)(pk);
        bf16x8 bh1 = *(const bf16x8*)(pk + 512);
        bf16x8 bh2 = *(const bf16x8*)(pk + 1024);
        bf16x8 bh3 = *(const bf16x8*)(pk + 1536);
        bf16x8 bl0 = *(const bf16x8*)(qk);
        bf16x8 bl1 = *(const bf16x8*)(qk + 512);
        bf16x8 bl2 = *(const bf16x8*)(qk + 1024);
        bf16x8 bl3 = *(const bf16x8*)(qk + 1536);

        f32x4 a0 = (f32x4){0.f, 0.f, 0.f, 0.f};
        f32x4 a1 = (f32x4){0.f, 0.f, 0.f, 0.f};
#define DT(BH, BL, D)                                                      \
        a0 = __builtin_amdgcn_mfma_f32_16x16x32_bf16(ah[0][D], BH, a0, 0, 0, 0); \
        a1 = __builtin_amdgcn_mfma_f32_16x16x32_bf16(ah[1][D], BH, a1, 0, 0, 0); \
        a0 = __builtin_amdgcn_mfma_f32_16x16x32_bf16(ah[0][D], BL, a0, 0, 0, 0); \
        a1 = __builtin_amdgcn_mfma_f32_16x16x32_bf16(ah[1][D], BL, a1, 0, 0, 0); \
        a0 = __builtin_amdgcn_mfma_f32_16x16x32_bf16(al[0][D], BH, a0, 0, 0, 0); \
        a1 = __builtin_amdgcn_mfma_f32_16x16x32_bf16(al[1][D], BH, a1, 0, 0, 0);
        DT(bh0, bl0, 0)
        DT(bh1, bl1, 1)
        DT(bh2, bl2, 2)
        DT(bh3, bl3, 3)
#undef DT

        float cq = csq[kk];
        nanf |= (cq != cq) ? 1 : 0;
        #pragma unroll
        for (int q = 0; q < 4; q++) {
            {
                float d = __fmaf_rn(-2.f, a0[q], cq);
                bool lt = (d < best1[q]);
                best2[q] = fminf(best2[q], lt ? best1[q] : d);
                if (lt) { best1[q] = d; bidx[q] = kk; }
            }
            {
                int s = 4 + q;
                float d = __fmaf_rn(-2.f, a1[q], cq);
                bool lt = (d < best1[s]);
                best2[s] = fminf(best2[s], lt ? best1[s] : d);
                if (lt) { best1[s] = d; bidx[s] = kk; }
            }
        }
        kk += 16;
    }

    // butterfly merge across the 16 cluster-lanes (same lane>>4 group)
    #pragma unroll
    for (int mask = 1; mask < 16; mask <<= 1) {
        #pragma unroll
        for (int s = 0; s < 8; s++) {
            float ob1 = __shfl_xor(best1[s], mask, 64);
            float ob2 = __shfl_xor(best2[s], mask, 64);
            int   oi  = __shfl_xor(bidx[s],  mask, 64);
            float nb2 = fminf(fminf(best2[s], ob2), fmaxf(best1[s], ob1));
            bool take = (ob1 < best1[s]) || (ob1 == best1[s] && oi < bidx[s]);
            if (take) { best1[s] = ob1; bidx[s] = oi; }
            best2[s] = nb2;
        }
    }

    int wnan = __any(nanf);
    if ((lane & 15) == 0) {
        int hi = lane >> 4;
        #pragma unroll
        for (int s = 0; s < 8; s++) {
            int p = bm + w * 32 + (s >> 2) * 16 + hi * 4 + (s & 3);
            bool fb = (wnan != 0) || !(best2[s] - best1[s] > THRESH);
            if (fb) { int pos = atomicAdd(fbc, 1); fb_list[pos] = p; }
            else cl[p] = bidx[s];
        }
    }
}

// frozen comparator: NaN acts as -inf tier, lowest index on ties (first-min/first-NaN)
__device__ __forceinline__ bool better(float od, int oi, float md, int mi) {
    bool n1 = (md != md), n2 = (od != od);
    if (n1 && n2) return oi < mi;
    if (n2) return true;
    if (n1) return false;
    return (od < md) || (od == md && oi < mi);
}

// ---- exact fallback: replay the frozen fp32 fmaf chain over all K.
// 16 points per block pass; d-loop unrolled 4x (16 centTf loads in flight).
// Unrolling interleaves INDEPENDENT (point,cluster) chains only -- each
// chain keeps its frozen d-ascending order. centTf[d][k] fp32 transposed
// -> coalesced; rounding identical to row-major chain. ----
__global__ __launch_bounds__(256) void fixup_kernel(
    const float* __restrict__ x, const float* __restrict__ centTf,
    const float* __restrict__ xsq, const float* __restrict__ csq,
    const int* __restrict__ fb_list, const int* __restrict__ fbc,
    int* __restrict__ cl)
{
    __shared__ float xs[16][DIM];   // 8 KB
    __shared__ float xqs[16];
    __shared__ int   ids[16];
    __shared__ float wv[16][4];
    __shared__ int   wi[16][4];
    const int t = threadIdx.x;
    const int lane = t & 63, wid = t >> 6;
    const int cnt = fbc[0];
    for (int w = blockIdx.x * 16; w < cnt; w += gridDim.x * 16) {
        int np = cnt - w; if (np > 16) np = 16;
        __syncthreads();                 // guard xs/wv reuse from prior pass
        if (t < np) { int i = fb_list[w + t]; ids[t] = i; xqs[t] = xsq[i]; }
        __syncthreads();
        for (int e = t; e < np * DIM; e += 256) {
            int p = e >> 7, d = e & 127;
            xs[p][d] = x[(size_t)ids[p] * DIM + d];
        }
        __syncthreads();
        float S[16][4];
        #pragma unroll
        for (int p = 0; p < 16; p++)
            #pragma unroll
            for (int c = 0; c < 4; c++) S[p][c] = 0.f;
        #pragma unroll 4
        for (int d = 0; d < DIM; d++) {
            const float* row = centTf + (size_t)d * KC;
            float c0 = row[t], c1 = row[t + 256], c2 = row[t + 512], c3 = row[t + 768];
            #pragma unroll
            for (int p = 0; p < 16; p++) {
                float xv = xs[p][d];
                S[p][0] = fmaf(xv, c0, S[p][0]);   // frozen chain, d ascending
                S[p][1] = fmaf(xv, c1, S[p][1]);
                S[p][2] = fmaf(xv, c2, S[p][2]);
                S[p][3] = fmaf(xv, c3, S[p][3]);
            }
        }
        float q0 = csq[t], q1 = csq[t + 256], q2 = csq[t + 512], q3 = csq[t + 768];
        #pragma unroll
        for (int p = 0; p < 16; p++) {
            float xq = xqs[p];
            float bb = INFINITY; int bi = 0x7fffffff;
            float dd; int c;
            c = t;       dd = __fadd_rn(__fsub_rn(xq, __fmul_rn(2.f, S[p][0])), q0); if (better(dd, c, bb, bi)) { bb = dd; bi = c; }
            c = t + 256; dd = __fadd_rn(__fsub_rn(xq, __fmul_rn(2.f, S[p][1])), q1); if (better(dd, c, bb, bi)) { bb = dd; bi = c; }
            c = t + 512; dd = __fadd_rn(__fsub_rn(xq, __fmul_rn(2.f, S[p][2])), q2); if (better(dd, c, bb, bi)) { bb = dd; bi = c; }
            c = t + 768; dd = __fadd_rn(__fsub_rn(xq, __fmul_rn(2.f, S[p][3])), q3); if (better(dd, c, bb, bi)) { bb = dd; bi = c; }
            #pragma unroll
            for (int mask = 1; mask < 64; mask <<= 1) {
                float od = __shfl_xor(bb, mask, 64);
                int   oi = __shfl_xor(bi, mask, 64);
                if (better(od, oi, bb, bi)) { bb = od; bi = oi; }
            }
            if (lane == 0) { wv[p][wid] = bb; wi[p][wid] = bi; }
        }
        __syncthreads();
        if (t < np) {
            float bb = wv[t][0]; int bi = wi[t][0];
            #pragma unroll
            for (int r = 1; r < 4; r++)
                if (better(wv[t][r], wi[t][r], bb, bi)) { bb = wv[t][r]; bi = wi[t][r]; }
            cl[ids[t]] = bi;
        }
    }
}

// ---- stable counting-scatter: list[] = per-cluster ascending point index ----

__global__ __launch_bounds__(256) void bhist_kernel(const int* __restrict__ cl,
                                                    int* __restrict__ bhist, int n,
                                                    int* __restrict__ fbc) {
    __shared__ int h[KC];
    int t = threadIdx.x;
    // fold the fbc reset here: bhist runs after fixup consumed fbc[0] and
    // before the next iteration's assign (stream order) -- race-free.
    if (blockIdx.x == 0 && t == 0) { fbc[0] = 0; fbc[1] = 0; }
    #pragma unroll
    for (int q = 0; q < KC / 256; q++) h[t + q * 256] = 0;
    __syncthreads();
    int i = blockIdx.x * 256 + t;
    if (i < n) atomicAdd(&h[cl[i]], 1);
    __syncthreads();
    int* row = bhist + (size_t)blockIdx.x * KC;
    #pragma unroll
    for (int q = 0; q < KC / 256; q++) row[t + q * 256] = h[t + q * 256];
}

__global__ __launch_bounds__(256) void colsum_kernel(const int* __restrict__ bhist,
                                                     int* __restrict__ cnt) {
    int k = blockIdx.x * 256 + threadIdx.x;
    int s = 0;
    for (int b = 0; b < NB; b++) s += bhist[(size_t)b * KC + k];
    cnt[k] = s;
}

__global__ void scan_kernel(const int* __restrict__ cnt, int* __restrict__ off) {
    __shared__ int s[KC];
    int t = threadIdx.x;
    s[t] = cnt[t];
    __syncthreads();
    for (int o = 1; o < KC; o <<= 1) {
        int v = (t >= o) ? s[t - o] : 0;
        __syncthreads();
        s[t] += v;
        __syncthreads();
    }
    off[t] = s[t] - cnt[t];
}

__global__ __launch_bounds__(256) void blockpfx_kernel(int* __restrict__ bhist,
                                                       const int* __restrict__ off) {
    int k = blockIdx.x * 256 + threadIdx.x;
    int run = off[k];
    for (int b = 0; b < NB; b++) {
        size_t idx = (size_t)b * KC + k;
        int t = bhist[idx];
        bhist[idx] = run;
        run += t;
    }
}

__global__ __launch_bounds__(256) void stable_scatter_kernel(
    const int* __restrict__ cl, const int* __restrict__ bhist,
    int* __restrict__ list, int n)
{
    __shared__ int cls[256];
    int t = threadIdx.x;
    int i = blockIdx.x * 256 + t;
    int c = (i < n) ? cl[i] : -1;
    cls[t] = c;
    __syncthreads();
    if (i >= n) return;
    int rank = 0;
    for (int j = 0; j < 256; j++)
        rank += (j < t && cls[j] == c) ? 1 : 0;
    list[bhist[(size_t)blockIdx.x * KC + c] + rank] = i;
}

// ---- segment sum: bitwise-ordered adds; writes cent, the bf16 hi/lo
// fragment-packed centP, the fp32 transposed centTf (fixup path), AND csq
// (frozen pairwise chain replayed from LDS -- removes a dispatch/iter) ----
#define CHUNK 512
__global__ __launch_bounds__(128) void sum_kernel(
    const float* __restrict__ x, const int* __restrict__ list,
    const int* __restrict__ off, const int* __restrict__ cnt,
    float* __restrict__ cent, ushort* __restrict__ centPh,
    ushort* __restrict__ centPl, float* __restrict__ centTf,
    float* __restrict__ csq, float* __restrict__ countsF)
{
    __attribute__((aligned(16))) __shared__ int sidx[CHUNK];   // 2 KB; reused below
    int k = blockIdx.x;
    int d = threadIdx.x;
    int o = off[k], m = cnt[k];
    float s = 0.f;
    for (int base = 0; base < m; base += CHUNK) {
        int c = m - base; if (c > CHUNK) c = CHUNK;
        __syncthreads();
        for (int t = d; t < c; t += 128) sidx[t] = list[o + base + t];
        __syncthreads();
        int j = 0;
        for (; j + 16 <= c; j += 16) {
            float v[16];
            #pragma unroll
            for (int u = 0; u < 16; u++)
                v[u] = x[(size_t)sidx[j + u] * DIM + d];
            #pragma unroll
            for (int u = 0; u < 16; u++)
                s = __fadd_rn(s, v[u]);
        }
        for (; j < c; j++)
            s = __fadd_rn(s, x[(size_t)sidx[j] * DIM + d]);
    }
    float mv = __fdiv_rn(s, (float)m);   // 0/0 -> NaN, matches ref
    cent[(size_t)k * DIM + d] = mv;
    centTf[(size_t)d * KC + k] = mv;
    unsigned short h = bf16rne(mv);
    unsigned short lo = bf16rne(__fsub_rn(mv, __uint_as_float(((unsigned int)h) << 16)));
    int pidx = (((k >> 4) * 4 + (d >> 5)) * 64 + ((k & 15) + 16 * ((d >> 3) & 3))) * 8 + (d & 7);
    centPh[pidx] = h;
    centPl[pidx] = lo;
    if (d == 0) countsF[k] = (float)m;
    // fused csq: replay the frozen pairwise chain on this centroid row
    __syncthreads();
    ((float*)sidx)[d] = mv;
    __syncthreads();
    if (d == 0) csq[k] = sq_np_row((const float*)sidx);
}

__global__ void init_centP_kernel(const float* __restrict__ x,
                                  ushort* __restrict__ centPh, ushort* __restrict__ centPl,
                                  float* __restrict__ centTf, int* __restrict__ fbc) {
    int i = blockIdx.x * 256 + threadIdx.x;
    if (i == 0) { fbc[0] = 0; fbc[1] = 0; }
    if (i < KC * DIM) {
        int k = i >> 7, d = i & 127;
        float v = x[i];
        centTf[(size_t)d * KC + k] = v;
        unsigned short h = bf16rne(v);
        unsigned short lo = bf16rne(__fsub_rn(v, __uint_as_float(((unsigned int)h) << 16)));
        int pidx = (((k >> 4) * 4 + (d >> 5)) * 64 + ((k & 15) + 16 * ((d >> 3) & 3))) * 8 + (d & 7);
        centPh[pidx] = h;
        centPl[pidx] = lo;
    }
}

__global__ void cl2f_kernel(const int* __restrict__ cl, float* __restrict__ out, int n) {
    int i = blockIdx.x * 256 + threadIdx.x;
    if (i < n) out[i] = (float)cl[i];
}

extern "C" void kernel_launch(void* const* d_in, const int* in_sizes, int n_in,
                              void* d_out, int out_size, void* d_ws, size_t ws_size,
                              hipStream_t stream) {
    const float* x = (const float*)d_in[0];
    const int n = in_sizes[0] / DIM;  // 131072

    // d_out: [clusters (N) | centroids (K*D) | counts (K)]
    float* clf     = (float*)d_out;
    float* cent    = clf + n;
    float* countsF = cent + KC * DIM;

    // ws scratch (~4.1 MB, same footprint as before)
    float* xsq   = (float*)d_ws;          // N
    float* csq   = xsq + n;               // K
    int*   cl    = (int*)(csq + KC);      // N
    int*   list  = cl + n;                // N (doubles as fb_list before scatter)
    int*   cnt   = list + n;              // K
    int*   off   = cnt + KC;              // K
    int*   bhist = off + KC;              // NB*K (2 MB)
    ushort* centPh = (ushort*)(bhist + (size_t)NB * KC);  // K*D bf16 hi (256 KB)
    ushort* centPl = centPh + KC * DIM;                   // K*D bf16 lo (256 KB)
    int*   fbc   = (int*)(centPl + KC * DIM);             // [count, cursor]
    // centTf (fp32 [D][K], 512 KB) ALIASES bhist: written by sum (end of
    // iter i) / init, read by fixup (early iter i+1), clobbered only by
    // bhist_kernel which runs after fixup in stream order. Time-disjoint.
    float* centTf = (float*)bhist;

    hipMemcpyAsync(cent, x, (size_t)KC * DIM * sizeof(float),
                   hipMemcpyDeviceToDevice, stream);
    init_centP_kernel<<<(KC * DIM + 255) / 256, 256, 0, stream>>>(x, centPh, centPl,
                                                                  centTf, fbc);
    sq_np_kernel<<<(n + 255) / 256, 256, 0, stream>>>(x, xsq, n);
    // iter-0 centroids are x[:K], so csq == xsq[:K] bit-exact (same chain)
    hipMemcpyAsync(csq, xsq, (size_t)KC * sizeof(float),
                   hipMemcpyDeviceToDevice, stream);

    for (int it = 0; it < NITER; it++) {
        assign_mfma_kernel<<<n / BM, 256, 0, stream>>>(x, centPh, centPl, csq,
                                                       cl, list, fbc);
        fixup_kernel<<<1024, 256, 0, stream>>>(x, centTf, xsq, csq, list, fbc, cl);
        bhist_kernel<<<NB, 256, 0, stream>>>(cl, bhist, n, fbc);
        colsum_kernel<<<KC / 256, 256, 0, stream>>>(bhist, cnt);
        scan_kernel<<<1, KC, 0, stream>>>(cnt, off);
        blockpfx_kernel<<<KC / 256, 256, 0, stream>>>(bhist, off);
        stable_scatter_kernel<<<NB, 256, 0, stream>>>(cl, bhist, list, n);
        sum_kernel<<<KC, DIM, 0, stream>>>(x, list, off, cnt, cent, centPh, centPl,
                                           centTf, csq, countsF);
    }

    cl2f_kernel<<<(n + 255) / 256, 256, 0, stream>>>(cl, clf, n);
}

// Round 11
// 2223.781 us; speedup vs baseline: 1.1285x; 1.0051x over previous
//
#include <hip/hip_runtime.h>
#include <math.h>

#define DIM 128
#define KC 1024
#define NITER 10
#define BM 128
#define NB 512   // scatter blocks: n / 256
#define THRESH 0.01f  // bf16 3-term screen-vs-frozen worst-case ~2e-3; 5x margin

typedef __bf16 bf16x8 __attribute__((ext_vector_type(8)));
typedef float f32x4 __attribute__((ext_vector_type(4)));

// round-to-nearest-even fp32 -> bf16 (NaN-preserving)
__device__ __forceinline__ unsigned short bf16rne(float f) {
    unsigned int u = __float_as_uint(f);
    unsigned int r = (u + 0x7FFFu + ((u >> 16) & 1u)) >> 16;
    return (unsigned short)r;
}

__device__ __forceinline__ bf16x8 pack_hi8(const float* fv, unsigned short* hs) {
    bf16x8 out;
    #pragma unroll
    for (int e = 0; e < 8; e++) {
        unsigned short h = bf16rne(fv[e]);
        hs[e] = h;
        out[e] = __builtin_bit_cast(__bf16, h);
    }
    return out;
}

// ---- numpy-pairwise sum of squares over one 128-float row, frozen chain.
// Shared by sq_np_kernel and the fused csq path in sum_kernel: the ops are
// exact IEEE (__fmul_rn/__fadd_rn) in a fixed order -> bit-exact anywhere.
__device__ __forceinline__ float sq_np_row(const float* __restrict__ v) {
    const float4* row = (const float4*)v;
    float r[8];
    {
        float4 a = row[0], b = row[1];
        r[0] = __fmul_rn(a.x, a.x); r[1] = __fmul_rn(a.y, a.y);
        r[2] = __fmul_rn(a.z, a.z); r[3] = __fmul_rn(a.w, a.w);
        r[4] = __fmul_rn(b.x, b.x); r[5] = __fmul_rn(b.y, b.y);
        r[6] = __fmul_rn(b.z, b.z); r[7] = __fmul_rn(b.w, b.w);
    }
    #pragma unroll
    for (int blk = 1; blk < 16; blk++) {
        float4 a = row[blk * 2], b = row[blk * 2 + 1];
        r[0] = __fadd_rn(r[0], __fmul_rn(a.x, a.x));
        r[1] = __fadd_rn(r[1], __fmul_rn(a.y, a.y));
        r[2] = __fadd_rn(r[2], __fmul_rn(a.z, a.z));
        r[3] = __fadd_rn(r[3], __fmul_rn(a.w, a.w));
        r[4] = __fadd_rn(r[4], __fmul_rn(b.x, b.x));
        r[5] = __fadd_rn(r[5], __fmul_rn(b.y, b.y));
        r[6] = __fadd_rn(r[6], __fmul_rn(b.z, b.z));
        r[7] = __fadd_rn(r[7], __fmul_rn(b.w, b.w));
    }
    return __fadd_rn(__fadd_rn(__fadd_rn(r[0], r[1]), __fadd_rn(r[2], r[3])),
                     __fadd_rn(__fadd_rn(r[4], r[5]), __fadd_rn(r[6], r[7])));
}

__global__ void sq_np_kernel(const float* __restrict__ v, float* __restrict__ out, int rows) {
    int i = blockIdx.x * blockDim.x + threadIdx.x;
    if (i >= rows) return;
    out[i] = sq_np_row(v + (size_t)i * DIM);
}

// ---- MFMA screen, register-resident A, zero LDS, zero barriers ----
// (R5/R7/R9-proven loop: bf16 3-term split, simple per-kt loads, compiler
// scheduling, VGPR 60, 4 waves/SIMD -- empirical optimum of 5 variants:
// LDS 270us / 512t 320us / THIS ~117us / f16 192us / sw-pipelined 163us.
// Cross-wave TLP hides L2 latency better than in-wave prefetch here.)
__global__ __launch_bounds__(256, 3) void assign_mfma_kernel(
    const float* __restrict__ x,
    const ushort* __restrict__ centPh, const ushort* __restrict__ centPl,
    const float* __restrict__ csq,
    int* __restrict__ cl, int* __restrict__ fb_list, int* __restrict__ fbc)
{
    const int tid = threadIdx.x;
    const int lane = tid & 63;
    const int w = tid >> 6;                 // wave 0..3 -> 32-point group
    const int bm = blockIdx.x * BM;
    const int row0 = bm + w * 32 + (lane & 15);
    const int ko = (lane >> 4) * 8;         // k-oct 0,8,16,24

    // ---- load + split A fragments (kt-invariant) ----
    bf16x8 ah[2][4], al[2][4];
    #pragma unroll
    for (int m = 0; m < 2; m++) {
        const float* xr = x + (size_t)(row0 + m * 16) * DIM;
        #pragma unroll
        for (int dt = 0; dt < 4; dt++) {
            float4 a = *(const float4*)(xr + dt * 32 + ko);
            float4 b = *(const float4*)(xr + dt * 32 + ko + 4);
            float fv[8] = {a.x, a.y, a.z, a.w, b.x, b.y, b.z, b.w};
            unsigned short hs[8];
            ah[m][dt] = pack_hi8(fv, hs);
            bf16x8 lo;
            #pragma unroll
            for (int e = 0; e < 8; e++) {
                float rem = __fsub_rn(fv[e], __uint_as_float(((unsigned int)hs[e]) << 16));
                lo[e] = __builtin_bit_cast(__bf16, bf16rne(rem));
            }
            al[m][dt] = lo;
        }
    }

    float best1[8], best2[8];
    int bidx[8];
    int nanf = 0;
    #pragma unroll
    for (int s = 0; s < 8; s++) { best1[s] = INFINITY; best2[s] = INFINITY; bidx[s] = 0; }

    const ushort* pb = centPh + lane * 8;
    const ushort* qb = centPl + lane * 8;
    int kk = lane & 15;

    for (int kt = 0; kt < KC / 16; kt++) {
        const ushort* pk = pb + (size_t)kt * 2048;
        const ushort* qk = qb + (size_t)kt * 2048;
        bf16x8 bh0 = *(const bf16x8*)(pk);
        bf16x8 bh1 = *(const bf16x8*)(pk + 512);
        bf16x8 bh2 = *(const bf16x8*)(pk + 1024);
        bf16x8 bh3 = *(const bf16x8*)(pk + 1536);
        bf16x8 bl0 = *(const bf16x8*)(qk);
        bf16x8 bl1 = *(const bf16x8*)(qk + 512);
        bf16x8 bl2 = *(const bf16x8*)(qk + 1024);
        bf16x8 bl3 = *(const bf16x8*)(qk + 1536);

        f32x4 a0 = (f32x4){0.f, 0.f, 0.f, 0.f};
        f32x4 a1 = (f32x4){0.f, 0.f, 0.f, 0.f};
#define DT(BH, BL, D)                                                      \
        a0 = __builtin_amdgcn_mfma_f32_16x16x32_bf16(ah[0][D], BH, a0, 0, 0, 0); \
        a1 = __builtin_amdgcn_mfma_f32_16x16x32_bf16(ah[1][D], BH, a1, 0, 0, 0); \
        a0 = __builtin_amdgcn_mfma_f32_16x16x32_bf16(ah[0][D], BL, a0, 0, 0, 0); \
        a1 = __builtin_amdgcn_mfma_f32_16x16x32_bf16(ah[1][D], BL, a1, 0, 0, 0); \
        a0 = __builtin_amdgcn_mfma_f32_16x16x32_bf16(al[0][D], BH, a0, 0, 0, 0); \
        a1 = __builtin_amdgcn_mfma_f32_16x16x32_bf16(al[1][D], BH, a1, 0, 0, 0);
        DT(bh0, bl0, 0)
        DT(bh1, bl1, 1)
        DT(bh2, bl2, 2)
        DT(bh3, bl3, 3)
#undef DT

        float cq = csq[kk];
        nanf |= (cq != cq) ? 1 : 0;
        #pragma unroll
        for (int q = 0; q < 4; q++) {
            {
                float d = __fmaf_rn(-2.f, a0[q], cq);
                bool lt = (d < best1[q]);
                best2[q] = fminf(best2[q], lt ? best1[q] : d);
                if (lt) { best1[q] = d; bidx[q] = kk; }
            }
            {
                int s = 4 + q;
                float d = __fmaf_rn(-2.f, a1[q], cq);
                bool lt = (d < best1[s]);
                best2[s] = fminf(best2[s], lt ? best1[s] : d);
                if (lt) { best1[s] = d; bidx[s] = kk; }
            }
        }
        kk += 16;
    }

    // butterfly merge across the 16 cluster-lanes (same lane>>4 group)
    #pragma unroll
    for (int mask = 1; mask < 16; mask <<= 1) {
        #pragma unroll
        for (int s = 0; s < 8; s++) {
            float ob1 = __shfl_xor(best1[s], mask, 64);
            float ob2 = __shfl_xor(best2[s], mask, 64);
            int   oi  = __shfl_xor(bidx[s],  mask, 64);
            float nb2 = fminf(fminf(best2[s], ob2), fmaxf(best1[s], ob1));
            bool take = (ob1 < best1[s]) || (ob1 == best1[s] && oi < bidx[s]);
            if (take) { best1[s] = ob1; bidx[s] = oi; }
            best2[s] = nb2;
        }
    }

    int wnan = __any(nanf);
    if ((lane & 15) == 0) {
        int hi = lane >> 4;
        #pragma unroll
        for (int s = 0; s < 8; s++) {
            int p = bm + w * 32 + (s >> 2) * 16 + hi * 4 + (s & 3);
            bool fb = (wnan != 0) || !(best2[s] - best1[s] > THRESH);
            if (fb) { int pos = atomicAdd(fbc, 1); fb_list[pos] = p; }
            else cl[p] = bidx[s];
        }
    }
}

// frozen comparator: NaN acts as -inf tier, lowest index on ties (first-min/first-NaN)
__device__ __forceinline__ bool better(float od, int oi, float md, int mi) {
    bool n1 = (md != md), n2 = (od != od);
    if (n1 && n2) return oi < mi;
    if (n2) return true;
    if (n1) return false;
    return (od < md) || (od == md && oi < mi);
}

// ---- exact fallback: replay the frozen fp32 fmaf chain over all K.
// 16 points per block pass; d-loop unrolled 4x (16 centTf loads in flight).
// Unrolling interleaves INDEPENDENT (point,cluster) chains only -- each
// chain keeps its frozen d-ascending order. centTf[d][k] fp32 transposed
// -> coalesced; rounding identical to row-major chain. ----
__global__ __launch_bounds__(256) void fixup_kernel(
    const float* __restrict__ x, const float* __restrict__ centTf,
    const float* __restrict__ xsq, const float* __restrict__ csq,
    const int* __restrict__ fb_list, const int* __restrict__ fbc,
    int* __restrict__ cl)
{
    __shared__ float xs[16][DIM];   // 8 KB
    __shared__ float xqs[16];
    __shared__ int   ids[16];
    __shared__ float wv[16][4];
    __shared__ int   wi[16][4];
    const int t = threadIdx.x;
    const int lane = t & 63, wid = t >> 6;
    const int cnt = fbc[0];
    for (int w = blockIdx.x * 16; w < cnt; w += gridDim.x * 16) {
        int np = cnt - w; if (np > 16) np = 16;
        __syncthreads();                 // guard xs/wv reuse from prior pass
        if (t < np) { int i = fb_list[w + t]; ids[t] = i; xqs[t] = xsq[i]; }
        __syncthreads();
        for (int e = t; e < np * DIM; e += 256) {
            int p = e >> 7, d = e & 127;
            xs[p][d] = x[(size_t)ids[p] * DIM + d];
        }
        __syncthreads();
        float S[16][4];
        #pragma unroll
        for (int p = 0; p < 16; p++)
            #pragma unroll
            for (int c = 0; c < 4; c++) S[p][c] = 0.f;
        #pragma unroll 4
        for (int d = 0; d < DIM; d++) {
            const float* row = centTf + (size_t)d * KC;
            float c0 = row[t], c1 = row[t + 256], c2 = row[t + 512], c3 = row[t + 768];
            #pragma unroll
            for (int p = 0; p < 16; p++) {
                float xv = xs[p][d];
                S[p][0] = fmaf(xv, c0, S[p][0]);   // frozen chain, d ascending
                S[p][1] = fmaf(xv, c1, S[p][1]);
                S[p][2] = fmaf(xv, c2, S[p][2]);
                S[p][3] = fmaf(xv, c3, S[p][3]);
            }
        }
        float q0 = csq[t], q1 = csq[t + 256], q2 = csq[t + 512], q3 = csq[t + 768];
        #pragma unroll
        for (int p = 0; p < 16; p++) {
            float xq = xqs[p];
            float bb = INFINITY; int bi = 0x7fffffff;
            float dd; int c;
            c = t;       dd = __fadd_rn(__fsub_rn(xq, __fmul_rn(2.f, S[p][0])), q0); if (better(dd, c, bb, bi)) { bb = dd; bi = c; }
            c = t + 256; dd = __fadd_rn(__fsub_rn(xq, __fmul_rn(2.f, S[p][1])), q1); if (better(dd, c, bb, bi)) { bb = dd; bi = c; }
            c = t + 512; dd = __fadd_rn(__fsub_rn(xq, __fmul_rn(2.f, S[p][2])), q2); if (better(dd, c, bb, bi)) { bb = dd; bi = c; }
            c = t + 768; dd = __fadd_rn(__fsub_rn(xq, __fmul_rn(2.f, S[p][3])), q3); if (better(dd, c, bb, bi)) { bb = dd; bi = c; }
            #pragma unroll
            for (int mask = 1; mask < 64; mask <<= 1) {
                float od = __shfl_xor(bb, mask, 64);
                int   oi = __shfl_xor(bi, mask, 64);
                if (better(od, oi, bb, bi)) { bb = od; bi = oi; }
            }
            if (lane == 0) { wv[p][wid] = bb; wi[p][wid] = bi; }
        }
        __syncthreads();
        if (t < np) {
            float bb = wv[t][0]; int bi = wi[t][0];
            #pragma unroll
            for (int r = 1; r < 4; r++)
                if (better(wv[t][r], wi[t][r], bb, bi)) { bb = wv[t][r]; bi = wi[t][r]; }
            cl[ids[t]] = bi;
        }
    }
}

// ---- stable counting-scatter: list[] = per-cluster ascending point index ----

__global__ __launch_bounds__(256) void bhist_kernel(const int* __restrict__ cl,
                                                    int* __restrict__ bhist, int n,
                                                    int* __restrict__ fbc) {
    __shared__ int h[KC];
    int t = threadIdx.x;
    // fold the fbc reset here: bhist runs after fixup consumed fbc[0] and
    // before the next iteration's assign (stream order) -- race-free.
    if (blockIdx.x == 0 && t == 0) { fbc[0] = 0; fbc[1] = 0; }
    #pragma unroll
    for (int q = 0; q < KC / 256; q++) h[t + q * 256] = 0;
    __syncthreads();
    int i = blockIdx.x * 256 + t;
    if (i < n) atomicAdd(&h[cl[i]], 1);
    __syncthreads();
    int* row = bhist + (size_t)blockIdx.x * KC;
    #pragma unroll
    for (int q = 0; q < KC / 256; q++) row[t + q * 256] = h[t + q * 256];
}

__global__ __launch_bounds__(256) void colsum_kernel(const int* __restrict__ bhist,
                                                     int* __restrict__ cnt) {
    int k = blockIdx.x * 256 + threadIdx.x;
    int s = 0;
    #pragma unroll 8
    for (int b = 0; b < NB; b++) s += bhist[(size_t)b * KC + k];
    cnt[k] = s;
}

// ---- fused scan + per-column block prefix.
// Each of the 4 blocks redundantly loads all 1024 cnt (4 KB, L2-hot),
// computes the exclusive column prefix (exact integer Hillis-Steele),
// writes off[] for its own 256 columns, then converts its bhist column
// to running global offsets with BATCHED loads (16 independent L2 loads
// in flight -- removes the old 512-deep serial-latency chain). ----
__global__ __launch_bounds__(256) void blockpfx_kernel(int* __restrict__ bhist,
                                                       const int* __restrict__ cnt,
                                                       int* __restrict__ off) {
    __shared__ int lc[KC];    // 4 KB: all cnt values
    __shared__ int ps[256];   // group (4-wide) sums scan
    int t = threadIdx.x;
    int4 cv = *(const int4*)(cnt + t * 4);
    *(int4*)(lc + t * 4) = cv;
    ps[t] = cv.x + cv.y + cv.z + cv.w;
    __syncthreads();
    for (int o = 1; o < 256; o <<= 1) {
        int v = (t >= o) ? ps[t - o] : 0;
        __syncthreads();
        ps[t] += v;
        __syncthreads();
    }
    int k = blockIdx.x * 256 + t;
    int g = k >> 2;
    int run = (g > 0) ? ps[g - 1] : 0;
    for (int j = g * 4; j < k; j++) run += lc[j];
    off[k] = run;   // blocks cover disjoint k ranges
    for (int b0 = 0; b0 < NB; b0 += 16) {
        int v[16];
        #pragma unroll
        for (int u = 0; u < 16; u++)
            v[u] = bhist[(size_t)(b0 + u) * KC + k];   // 16 loads in flight
        #pragma unroll
        for (int u = 0; u < 16; u++) {
            bhist[(size_t)(b0 + u) * KC + k] = run;
            run += v[u];
        }
    }
}

__global__ __launch_bounds__(256) void stable_scatter_kernel(
    const int* __restrict__ cl, const int* __restrict__ bhist,
    int* __restrict__ list, int n)
{
    __shared__ int cls[256];
    int t = threadIdx.x;
    int i = blockIdx.x * 256 + t;
    int c = (i < n) ? cl[i] : -1;
    cls[t] = c;
    __syncthreads();
    if (i >= n) return;
    int rank = 0;
    for (int j = 0; j < 256; j++)
        rank += (j < t && cls[j] == c) ? 1 : 0;
    list[bhist[(size_t)blockIdx.x * KC + c] + rank] = i;
}

// ---- segment sum: bitwise-ordered adds; writes cent, the bf16 hi/lo
// fragment-packed centP, the fp32 transposed centTf (fixup path), AND csq
// (frozen pairwise chain replayed from LDS -- removes a dispatch/iter) ----
#define CHUNK 512
__global__ __launch_bounds__(128) void sum_kernel(
    const float* __restrict__ x, const int* __restrict__ list,
    const int* __restrict__ off, const int* __restrict__ cnt,
    float* __restrict__ cent, ushort* __restrict__ centPh,
    ushort* __restrict__ centPl, float* __restrict__ centTf,
    float* __restrict__ csq, float* __restrict__ countsF)
{
    __attribute__((aligned(16))) __shared__ int sidx[CHUNK];   // 2 KB; reused below
    int k = blockIdx.x;
    int d = threadIdx.x;
    int o = off[k], m = cnt[k];
    float s = 0.f;
    for (int base = 0; base < m; base += CHUNK) {
        int c = m - base; if (c > CHUNK) c = CHUNK;
        __syncthreads();
        for (int t = d; t < c; t += 128) sidx[t] = list[o + base + t];
        __syncthreads();
        int j = 0;
        for (; j + 16 <= c; j += 16) {
            float v[16];
            #pragma unroll
            for (int u = 0; u < 16; u++)
                v[u] = x[(size_t)sidx[j + u] * DIM + d];
            #pragma unroll
            for (int u = 0; u < 16; u++)
                s = __fadd_rn(s, v[u]);
        }
        for (; j < c; j++)
            s = __fadd_rn(s, x[(size_t)sidx[j] * DIM + d]);
    }
    float mv = __fdiv_rn(s, (float)m);   // 0/0 -> NaN, matches ref
    cent[(size_t)k * DIM + d] = mv;
    centTf[(size_t)d * KC + k] = mv;
    unsigned short h = bf16rne(mv);
    unsigned short lo = bf16rne(__fsub_rn(mv, __uint_as_float(((unsigned int)h) << 16)));
    int pidx = (((k >> 4) * 4 + (d >> 5)) * 64 + ((k & 15) + 16 * ((d >> 3) & 3))) * 8 + (d & 7);
    centPh[pidx] = h;
    centPl[pidx] = lo;
    if (d == 0) countsF[k] = (float)m;
    // fused csq: replay the frozen pairwise chain on this centroid row
    __syncthreads();
    ((float*)sidx)[d] = mv;
    __syncthreads();
    if (d == 0) csq[k] = sq_np_row((const float*)sidx);
}

__global__ void init_centP_kernel(const float* __restrict__ x,
                                  ushort* __restrict__ centPh, ushort* __restrict__ centPl,
                                  float* __restrict__ centTf, int* __restrict__ fbc) {
    int i = blockIdx.x * 256 + threadIdx.x;
    if (i == 0) { fbc[0] = 0; fbc[1] = 0; }
    if (i < KC * DIM) {
        int k = i >> 7, d = i & 127;
        float v = x[i];
        centTf[(size_t)d * KC + k] = v;
        unsigned short h = bf16rne(v);
        unsigned short lo = bf16rne(__fsub_rn(v, __uint_as_float(((unsigned int)h) << 16)));
        int pidx = (((k >> 4) * 4 + (d >> 5)) * 64 + ((k & 15) + 16 * ((d >> 3) & 3))) * 8 + (d & 7);
        centPh[pidx] = h;
        centPl[pidx] = lo;
    }
}

__global__ void cl2f_kernel(const int* __restrict__ cl, float* __restrict__ out, int n) {
    int i = blockIdx.x * 256 + threadIdx.x;
    if (i < n) out[i] = (float)cl[i];
}

extern "C" void kernel_launch(void* const* d_in, const int* in_sizes, int n_in,
                              void* d_out, int out_size, void* d_ws, size_t ws_size,
                              hipStream_t stream) {
    const float* x = (const float*)d_in[0];
    const int n = in_sizes[0] / DIM;  // 131072

    // d_out: [clusters (N) | centroids (K*D) | counts (K)]
    float* clf     = (float*)d_out;
    float* cent    = clf + n;
    float* countsF = cent + KC * DIM;

    // ws scratch (~4.1 MB, same footprint as before)
    float* xsq   = (float*)d_ws;          // N
    float* csq   = xsq + n;               // K
    int*   cl    = (int*)(csq + KC);      // N
    int*   list  = cl + n;                // N (doubles as fb_list before scatter)
    int*   cnt   = list + n;              // K
    int*   off   = cnt + KC;              // K
    int*   bhist = off + KC;              // NB*K (2 MB)
    ushort* centPh = (ushort*)(bhist + (size_t)NB * KC);  // K*D bf16 hi (256 KB)
    ushort* centPl = centPh + KC * DIM;                   // K*D bf16 lo (256 KB)
    int*   fbc   = (int*)(centPl + KC * DIM);             // [count, cursor]
    // centTf (fp32 [D][K], 512 KB) ALIASES bhist: written by sum (end of
    // iter i) / init, read by fixup (early iter i+1), clobbered only by
    // bhist_kernel which runs after fixup in stream order. Time-disjoint.
    float* centTf = (float*)bhist;

    hipMemcpyAsync(cent, x, (size_t)KC * DIM * sizeof(float),
                   hipMemcpyDeviceToDevice, stream);
    init_centP_kernel<<<(KC * DIM + 255) / 256, 256, 0, stream>>>(x, centPh, centPl,
                                                                  centTf, fbc);
    sq_np_kernel<<<(n + 255) / 256, 256, 0, stream>>>(x, xsq, n);
    // iter-0 centroids are x[:K], so csq == xsq[:K] bit-exact (same chain)
    hipMemcpyAsync(csq, xsq, (size_t)KC * sizeof(float),
                   hipMemcpyDeviceToDevice, stream);

    for (int it = 0; it < NITER; it++) {
        assign_mfma_kernel<<<n / BM, 256, 0, stream>>>(x, centPh, centPl, csq,
                                                       cl, list, fbc);
        fixup_kernel<<<1024, 256, 0, stream>>>(x, centTf, xsq, csq, list, fbc, cl);
        bhist_kernel<<<NB, 256, 0, stream>>>(cl, bhist, n, fbc);
        colsum_kernel<<<KC / 256, 256, 0, stream>>>(bhist, cnt);
        blockpfx_kernel<<<KC / 256, 256, 0, stream>>>(bhist, cnt, off);
        stable_scatter_kernel<<<NB, 256, 0, stream>>>(cl, bhist, list, n);
        sum_kernel<<<KC, DIM, 0, stream>>>(x, list, off, cnt, cent, centPh, centPl,
                                           centTf, csq, countsF);
    }

    cl2f_kernel<<<(n + 255) / 256, 256, 0, stream>>>(cl, clf, n);
}